// Round 3
// baseline (162.647 us; speedup 1.0000x reference)
//
#include <hip/hip_runtime.h>

// Masked embedding gather:
//   idx = x[i]; if (idx % 2 == 0) idx = 0;  out[i, :] = emb[idx, :]
// x: (8, 4096) int32, emb: (50257, 512) fp32, out: (8, 4096, 512) fp32.
//
// R3 = R2 with the compile fix: __builtin_nontemporal_store needs a native
// clang vector type, not HIP's float4 class. Use ext_vector_type(4) float.
//
// R2 theory (request-count):
//  - Row 0 cached in registers once per wave; even tokens (~50% of tokens ->
//    50% of gather loads) served from registers. Halves VMEM gather
//    instruction count and ~32 MB of L2->CU traffic.
//  - Nontemporal stores for out (67 MB pure streaming): keep L2 for gathers.
//  - TPW=4, 256-thread blocks -> 8192 waves = 32 waves/CU max TLP.

#define EMB 512
#define TPW 4   // tokens per wave

typedef float vf4 __attribute__((ext_vector_type(4)));

__global__ __launch_bounds__(256) void embed_gather_kernel(
    const int* __restrict__ x,
    const float* __restrict__ emb,
    float* __restrict__ out,
    int n_tokens)
{
    const int wid  = (blockIdx.x * blockDim.x + threadIdx.x) >> 6;  // global wave id
    const int lane = threadIdx.x & 63;
    const int tbase = wid * TPW;
    if (tbase >= n_tokens) return;

    // Row 0 once per wave (L2 hit after the first wave touches it).
    const vf4* __restrict__ r0 = (const vf4*)emb;
    const vf4 z0 = r0[lane];
    const vf4 z1 = r0[lane + 64];

    if (tbase + TPW <= n_tokens) {
        // ---- fast path: full group of TPW tokens ----
        // lanes 0..TPW-1 hold the token ids (one 16 B segment -> 1 request)
        int id = x[tbase + (lane & (TPW - 1))];
        id = (id & 1) ? id : 0;                 // even ids -> row 0

        vf4 v[TPW][2];
        #pragma unroll
        for (int i = 0; i < TPW; ++i) {
            const int row = __shfl(id, i, 64);  // wave-uniform row index
            if (row != 0) {                     // uniform branch
                const vf4* __restrict__ src = (const vf4*)(emb + (size_t)row * EMB);
                v[i][0] = src[lane];            // 128 vf4 per row, 2 per lane
                v[i][1] = src[lane + 64];
            } else {
                v[i][0] = z0;                   // served from registers
                v[i][1] = z1;
            }
        }
        #pragma unroll
        for (int i = 0; i < TPW; ++i) {
            vf4* __restrict__ dst = (vf4*)(out + (size_t)(tbase + i) * EMB);
            __builtin_nontemporal_store(v[i][0], &dst[lane]);
            __builtin_nontemporal_store(v[i][1], &dst[lane + 64]);
        }
    } else {
        // ---- tail path (not taken for n_tokens = 32768) ----
        for (int t = tbase; t < n_tokens; ++t) {
            int id = x[t];
            if ((id & 1) == 0) id = 0;
            vf4* __restrict__ dst = (vf4*)(out + (size_t)t * EMB);
            if (id != 0) {
                const vf4* __restrict__ src = (const vf4*)(emb + (size_t)id * EMB);
                __builtin_nontemporal_store(src[lane],      &dst[lane]);
                __builtin_nontemporal_store(src[lane + 64], &dst[lane + 64]);
            } else {
                __builtin_nontemporal_store(z0, &dst[lane]);
                __builtin_nontemporal_store(z1, &dst[lane + 64]);
            }
        }
    }
}

extern "C" void kernel_launch(void* const* d_in, const int* in_sizes, int n_in,
                              void* d_out, int out_size, void* d_ws, size_t ws_size,
                              hipStream_t stream)
{
    const int* x = (const int*)d_in[0];          // (8, 4096) int32
    const float* emb = (const float*)d_in[1];    // (50257, 512) fp32
    float* out = (float*)d_out;                  // (8, 4096, 512) fp32

    const int n_tokens = in_sizes[0];            // 32768
    const int tokens_per_block = (256 / 64) * TPW;  // 4 waves x 4 tokens = 16
    const int blocks = (n_tokens + tokens_per_block - 1) / tokens_per_block;

    embed_gather_kernel<<<blocks, 256, 0, stream>>>(x, emb, out, n_tokens);
}